// Round 4
// baseline (1475.242 us; speedup 1.0000x reference)
//
#include <hip/hip_runtime.h>
#include <math.h>

// SLSTM: T=1024, B=256, C=14, H=128, 4H=512, NC=7. fp32 in/out.
//
// Round 15 = R14 with the time axis split 2x finer and 2 blocks per batch:
//   - 32 chunks x 32 steps; block half=0 owns t 0..511, half=1 owns 512..1023.
//     Each block keeps the SAME 16-chunk / 8-wave / per-step code as R14.
//   - NSTEP = W_UP + 33 = 73 (was 105): -30% serial steps.
//   - grid 512, LDS/block ~56 KB -> 2 blocks/CU, 4 waves/SIMD: stalls
//     (spike-load chains, ds_read latency, barriers) hide across blocks.
//   - partial sums -> sums[2][B][H]; fc_kernel adds the two halves.
// Spike loop / WT / W_UP=40 unchanged from R14 for clean attribution.

#define T_STEPS 1024
#define BATCH   256
#define H       128
#define NC      7
#define W_UP    40
#define CHUNK   32
#define NSTEP   (W_UP + CHUNK + 1)   // 73
#define XROWS   576                  // [t0-64, t0+512): lt = 32c + r + 24

typedef __attribute__((ext_vector_type(8))) _Float16 f16x8;
typedef __attribute__((ext_vector_type(4))) float f32x4;

__device__ __forceinline__ float frcp(float v) { return __builtin_amdgcn_rcpf(v); }
__device__ __forceinline__ float fsig(float v) { return frcp(1.f + __expf(-v)); }
__device__ __forceinline__ float ftanh(float v) {
  return 1.f - 2.f * frcp(__expf(2.f * v) + 1.f);
}
__device__ __forceinline__ unsigned fpk(float a, float b) {
  unsigned lo = (unsigned)__builtin_bit_cast(unsigned short, (_Float16)a);
  unsigned hi = (unsigned)__builtin_bit_cast(unsigned short, (_Float16)b);
  return lo | (hi << 16);
}
__device__ __forceinline__ unsigned short f16b(float v) {
  return __builtin_bit_cast(unsigned short, (_Float16)v);
}
#define MFMA16(A, B, C) __builtin_amdgcn_mfma_f32_16x16x32_f16(A, B, C, 0, 0, 0)

__device__ __forceinline__ f16x8 ldb8(const float* p) {
  float4 a = *(const float4*)p, b = *(const float4*)(p + 4);
  f16x8 r;
  r[0] = (_Float16)a.x; r[1] = (_Float16)a.y; r[2] = (_Float16)a.z; r[3] = (_Float16)a.w;
  r[4] = (_Float16)b.x; r[5] = (_Float16)b.y; r[6] = (_Float16)b.z; r[7] = (_Float16)b.w;
  return r;
}

// -------------------------------------------------- Wih2 transpose (once)
// WT[k*512 + h*4 + ti] = Wih2[(ti*128 + h)*128 + k]; 64K floats = 256 KB.
__global__ void w2t_kernel(const float* __restrict__ Wih2,
                           float* __restrict__ WT)
{
  int idx = blockIdx.x * 256 + threadIdx.x;      // 65536 total
  int k  = idx >> 9;
  int h  = (idx >> 2) & 127;
  int ti = idx & 3;
  WT[idx] = Wih2[(size_t)(ti * 128 + h) * 128 + k];
}

// ------------------------------------------------------------- fused SLSTM
__global__ __launch_bounds__(512)
__attribute__((amdgpu_waves_per_eu(4, 4)))
void slstm_kernel(
    const float* __restrict__ x,      // [T,B,14]
    const float* __restrict__ Wih1,   // [512,14]
    const float* __restrict__ Whh1,   // [512,128]
    const float* __restrict__ bih1, const float* __restrict__ bhh1,
    const float* __restrict__ thr1p,
    const float* __restrict__ WT,     // [128,128,4] transposed Wih2
    const float* __restrict__ Whh2,   // [512,128]
    const float* __restrict__ bih2, const float* __restrict__ bhh2,
    const float* __restrict__ thr2p,
    float* __restrict__ sums)         // [2,B,H]
{
  const int b    = blockIdx.x >> 1;
  const int half = blockIdx.x & 1;
  const int j    = threadIdx.x;
  const int lane = j & 63;
  const int w    = j >> 6;
  const int c    = lane & 15;        // MFMA col within 16-tile / A-row (chunk)
  const int q    = lane >> 4;        // quad (k-slice / acc m-row group)
  const int h    = w * 16 + c;       // this thread's gate column (h index)
  const int qr   = (q ^ (c >> 2)) * 8;     // swizzled k-slot for mb reads
  const int hsw  = h ^ (q << 3);           // swizzled h for mb writes
  const int t0   = half * 512 - 64;        // xb row lt = t - t0

  __shared__ __align__(16) unsigned xb[XROWS * 16];          // 36.9 KB f16 pairs
  __shared__ __align__(16) unsigned short mb1[2][16 * 144];  // mem1 f16, dbuf
  __shared__ __align__(16) unsigned short mb2[2][16 * 144];  // mem2 f16, dbuf
  __shared__ __align__(16) unsigned short smk[2][16][8];     // spk1 bit-fields

  // ---- resident B fragments (n = ti*128 + h; ti = gate type)
  f16x8 B1h[4][4], B1x[4], B2h[4][4];
  float bias1v[4], bias2v[4];
#pragma unroll
  for (int ti = 0; ti < 4; ++ti) {
    const int n = ti * 128 + h;
#pragma unroll
    for (int kt = 0; kt < 4; ++kt) {
      B1h[ti][kt] = ldb8(Whh1 + (size_t)n * 128 + kt * 32 + q * 8);
      B2h[ti][kt] = ldb8(Whh2 + (size_t)n * 128 + kt * 32 + q * 8);
    }
    f16x8 bx;
#pragma unroll
    for (int e = 0; e < 8; ++e) {
      int k = q * 8 + e;
      bx[e] = (k < 14) ? (_Float16)Wih1[n * 14 + k] : (_Float16)0.f;
    }
    B1x[ti] = bx;
    bias1v[ti] = bih1[n] + bhh1[n];
    bias2v[ti] = bih2[n] + bhh2[n];
  }
  const float thr1 = thr1p[0], thr2 = thr2p[0];
  const float* wt4 = WT + h * 4;     // + k*512 (+ ti)

  // ---- stage this block's x window as f16 pairs, word-swizzled by (lt>>6)&3
  for (int m = j; m < XROWS * 16; m += 512) {
    int lt = m >> 4, p = m & 15;
    int t = t0 + lt;
    if (t < 0) t = 0;                // rows lt<24 are never read
    unsigned v = 0;
    if (p < 7) {
      const float* xp = x + ((size_t)t * BATCH + b) * 14 + 2 * p;
      v = fpk(xp[0], xp[1]);
    }
    xb[(lt << 4) | (p ^ (((lt >> 6) & 3) << 2))] = v;
  }
  {
    unsigned short* z1 = &mb1[0][0];
    unsigned short* z2 = &mb2[0][0];
    for (int m = j; m < 2 * 16 * 144; m += 512) { z1[m] = 0; z2[m] = 0; }
    unsigned short* zs = &smk[0][0][0];
    for (int m = j; m < 2 * 16 * 8; m += 512) zs[m] = 0;
  }

  float syn1[4] = {0,0,0,0}, mem1[4] = {0,0,0,0};
  float syn2[4] = {0,0,0,0}, mem2[4] = {0,0,0,0}, sum2[4] = {0,0,0,0};
  __syncthreads();

  for (int r = 0; r < NSTEP; ++r) {
    const int cb = r & 1, pb = cb ^ 1;
    const bool do1 = (r < NSTEP - 1);
    const bool do2 = (r > 0);

    // ---------------- layer 1: gates + thread-local state update
    if (do1) {
      f16x8 A[5];
#pragma unroll
      for (int kt = 0; kt < 4; ++kt)
        A[kt] = *(const f16x8*)&mb1[pb][c * 144 + kt * 32 + qr];
      int lt = CHUNK * c + r + (64 - W_UP);   // in [24, 575]
      A[4] = *(const f16x8*)&xb[(lt << 4) | ((q ^ ((lt >> 6) & 3)) << 2)];
      f32x4 acc[4];
#pragma unroll
      for (int ti = 0; ti < 4; ++ti) {
        acc[ti][0] = bias1v[ti]; acc[ti][1] = bias1v[ti];
        acc[ti][2] = bias1v[ti]; acc[ti][3] = bias1v[ti];
      }
#pragma unroll
      for (int kt = 0; kt < 4; ++kt) {
        acc[0] = MFMA16(A[kt], B1h[0][kt], acc[0]);
        acc[1] = MFMA16(A[kt], B1h[1][kt], acc[1]);
        acc[2] = MFMA16(A[kt], B1h[2][kt], acc[2]);
        acc[3] = MFMA16(A[kt], B1h[3][kt], acc[3]);
      }
      acc[0] = MFMA16(A[4], B1x[0], acc[0]);
      acc[1] = MFMA16(A[4], B1x[1], acc[1]);
      acc[2] = MFMA16(A[4], B1x[2], acc[2]);
      acc[3] = MFMA16(A[4], B1x[3], acc[3]);
      bool sp[4];
#pragma unroll
      for (int i = 0; i < 4; ++i) {
        float iv = fsig(acc[0][i]);
        float fv = fsig(acc[1][i]);
        float gv = ftanh(acc[2][i]);
        float ov = fsig(acc[3][i]);
        syn1[i] = fv * syn1[i] + iv * gv;
        float rst = (mem1[i] - thr1 > 0.f) ? thr1 : 0.f;   // detached pre-update
        mem1[i] = ov * ftanh(syn1[i]) - rst;
        if (half == 0 && CHUNK * (4 * q + i) + r < W_UP)   // t<0: no history
          { syn1[i] = 0.f; mem1[i] = 0.f; }
        sp[i] = (mem1[i] - thr1) > 0.f;
        mb1[cb][(4 * q + i) * 144 + hsw] = f16b(mem1[i]);
      }
      unsigned long long g0 = __ballot(sp[0]), g1 = __ballot(sp[1]);
      unsigned long long g2 = __ballot(sp[2]), g3 = __ballot(sp[3]);
      if (c == 0) {   // lane 16q extracts its q's 16-bit field for chunk 4q+i
        smk[cb][4 * q + 0][w] = (unsigned short)(g0 >> (16 * q));
        smk[cb][4 * q + 1][w] = (unsigned short)(g1 >> (16 * q));
        smk[cb][4 * q + 2][w] = (unsigned short)(g2 >> (16 * q));
        smk[cb][4 * q + 3][w] = (unsigned short)(g3 >> (16 * q));
      }
    }

    // ---------------- layer 2 (one step behind): spikes + gates + state
    if (do2) {
      f32x4 acc[4];
#pragma unroll
      for (int ti = 0; ti < 4; ++ti) {
        acc[ti][0] = bias2v[ti]; acc[ti][1] = bias2v[ti];
        acc[ti][2] = bias2v[ti]; acc[ti][3] = bias2v[ti];
      }
      // spike input: one coalesced float4 (i,f,g,o weights) per set bit
#pragma unroll
      for (int i = 0; i < 4; ++i) {
        const unsigned long long* mp =
            (const unsigned long long*)&smk[pb][4 * q + i][0];
        unsigned long long m0 = mp[0], m1 = mp[1];
        float a0 = 0.f, a1 = 0.f, a2 = 0.f, a3 = 0.f;
        while (m0) {
          int k = __builtin_ctzll(m0); m0 &= m0 - 1;
          float4 v = *(const float4*)(wt4 + (k << 9));
          a0 += v.x; a1 += v.y; a2 += v.z; a3 += v.w;
        }
        while (m1) {
          int k = 64 + __builtin_ctzll(m1); m1 &= m1 - 1;
          float4 v = *(const float4*)(wt4 + (k << 9));
          a0 += v.x; a1 += v.y; a2 += v.z; a3 += v.w;
        }
        acc[0][i] += a0; acc[1][i] += a1; acc[2][i] += a2; acc[3][i] += a3;
      }
      f16x8 A[4];
#pragma unroll
      for (int kt = 0; kt < 4; ++kt)
        A[kt] = *(const f16x8*)&mb2[pb][c * 144 + kt * 32 + qr];
#pragma unroll
      for (int kt = 0; kt < 4; ++kt) {
        acc[0] = MFMA16(A[kt], B2h[0][kt], acc[0]);
        acc[1] = MFMA16(A[kt], B2h[1][kt], acc[1]);
        acc[2] = MFMA16(A[kt], B2h[2][kt], acc[2]);
        acc[3] = MFMA16(A[kt], B2h[3][kt], acc[3]);
      }
      const bool inwin = (r > W_UP);
#pragma unroll
      for (int i = 0; i < 4; ++i) {
        float iv = fsig(acc[0][i]);
        float fv = fsig(acc[1][i]);
        float gv = ftanh(acc[2][i]);
        float ov = fsig(acc[3][i]);
        syn2[i] = fv * syn2[i] + iv * gv;
        float rst = (mem2[i] - thr2 > 0.f) ? thr2 : 0.f;
        mem2[i] = ov * ftanh(syn2[i]) - rst;
        if (half == 0 && CHUNK * (4 * q + i) + r - 1 < W_UP)
          { syn2[i] = 0.f; mem2[i] = 0.f; }
        if (inwin) sum2[i] += mem2[i];
        mb2[cb][(4 * q + i) * 144 + hsw] = f16b(mem2[i]);
      }
    }
    __syncthreads();
  }

  // ---- per-h reduction over the 4 q-groups: pure shuffle, no LDS
  float s = (sum2[0] + sum2[1]) + (sum2[2] + sum2[3]);
  s += __shfl_xor(s, 16);
  s += __shfl_xor(s, 32);
  if (q == 0)
    sums[((size_t)half * BATCH + b) * H + h] = s;
}

// ---------------------------------------------------------------- readout
__global__ void fc_kernel(const float* __restrict__ sumbuf,  // [2,B,H]
                          const float* __restrict__ fcw,     // [NC,H]
                          const float* __restrict__ fcb,
                          float* __restrict__ out)           // [B,NC]
{
  int g = blockIdx.x * blockDim.x + threadIdx.x;
  if (g >= BATCH * NC) return;
  int b = g / NC, c = g % NC;
  const float* s0 = sumbuf + (size_t)b * H;
  const float* s1 = sumbuf + (size_t)(BATCH + b) * H;
  const float* wr = fcw + c * H;
  float acc = 0.f;
#pragma unroll
  for (int hh = 0; hh < H; hh += 4) {
    float4 a = *(const float4*)(s0 + hh);
    float4 bv = *(const float4*)(s1 + hh);
    float4 wv = *(const float4*)(wr + hh);
    acc += (a.x + bv.x) * wv.x + (a.y + bv.y) * wv.y +
           (a.z + bv.z) * wv.z + (a.w + bv.w) * wv.w;
  }
  out[g] = fcb[c] + acc * (1.f / 1024.f);
}

extern "C" void kernel_launch(void* const* d_in, const int* in_sizes, int n_in,
                              void* d_out, int out_size, void* d_ws, size_t ws_size,
                              hipStream_t stream)
{
  (void)in_sizes; (void)n_in; (void)out_size; (void)ws_size;
  const float* x    = (const float*)d_in[0];
  const float* Wih1 = (const float*)d_in[1];
  const float* Whh1 = (const float*)d_in[2];
  const float* bih1 = (const float*)d_in[3];
  const float* bhh1 = (const float*)d_in[4];
  const float* thr1 = (const float*)d_in[5];
  const float* Wih2 = (const float*)d_in[6];
  const float* Whh2 = (const float*)d_in[7];
  const float* bih2 = (const float*)d_in[8];
  const float* bhh2 = (const float*)d_in[9];
  const float* thr2 = (const float*)d_in[10];
  const float* fcw  = (const float*)d_in[11];
  const float* fcb  = (const float*)d_in[12];

  float* sums = (float*)d_ws;                          // [2,B,H] = 256 KB
  float* WT   = (float*)((char*)d_ws + 256 * 1024);    // 256 KB

  w2t_kernel<<<256, 256, 0, stream>>>(Wih2, WT);
  slstm_kernel<<<512, 512, 0, stream>>>(x, Wih1, Whh1, bih1, bhh1, thr1,
                                        WT, Whh2, bih2, bhh2, thr2, sums);
  fc_kernel<<<(BATCH * NC + 255) / 256, 256, 0, stream>>>(sums, fcw, fcb,
                                                          (float*)d_out);
}

// Round 5
// 318.107 us; speedup vs baseline: 4.6376x; 4.6376x over previous
//
#include <hip/hip_runtime.h>
#include <math.h>

// SLSTM: T=1024, B=256, C=14, H=128, 4H=512, NC=7. fp32 in/out.
//
// Round 16 = R14 (16 chunks x 64 steps, NSTEP=105, 275 us) restructured as a
// WAVE-SPECIALIZED 1024-thread block (R15's 2-block split reverted - it
// forced 4 waves/EU on waves holding BOTH layers' weights, 144 regs spilled,
// 4.3 GB scratch traffic):
//   - waves 0..7  : layer 1 only (B1h 64 + B1x16 8 regs resident)
//   - waves 8..15 : layer 2 only (B2h 64 regs resident + WT spike loop)
//   Each path fits the 128-reg cap of 16 waves/CU -> 4 waves/SIMD of
//   latency hiding WITH register-resident weights. Same smk/mb LDS flow,
//   one barrier/step (barrier counts match across the wave-uniform branch).
//   - x MFMA switched to K=16 mfma_f32_16x16x16f16: B1x frags 16->8 regs,
//     xb rows 16->8 words (32 KB; LDS total ~50 KB).

#define T_STEPS 1024
#define BATCH   256
#define H       128
#define NC      7
#define W_UP    40
#define NSTEP   (W_UP + 65)   // 105

typedef __attribute__((ext_vector_type(8))) _Float16 f16x8;
typedef __attribute__((ext_vector_type(4))) _Float16 f16x4;
typedef __attribute__((ext_vector_type(4))) float f32x4;

__device__ __forceinline__ float frcp(float v) { return __builtin_amdgcn_rcpf(v); }
__device__ __forceinline__ float fsig(float v) { return frcp(1.f + __expf(-v)); }
__device__ __forceinline__ float ftanh(float v) {
  return 1.f - 2.f * frcp(__expf(2.f * v) + 1.f);
}
__device__ __forceinline__ unsigned fpk(float a, float b) {
  unsigned lo = (unsigned)__builtin_bit_cast(unsigned short, (_Float16)a);
  unsigned hi = (unsigned)__builtin_bit_cast(unsigned short, (_Float16)b);
  return lo | (hi << 16);
}
__device__ __forceinline__ unsigned short f16b(float v) {
  return __builtin_bit_cast(unsigned short, (_Float16)v);
}
#define MFMA16(A, B, C) __builtin_amdgcn_mfma_f32_16x16x32_f16(A, B, C, 0, 0, 0)
#define MFMAX(A, B, C)  __builtin_amdgcn_mfma_f32_16x16x16f16(A, B, C, 0, 0, 0)

__device__ __forceinline__ f16x8 ldb8(const float* p) {
  float4 a = *(const float4*)p, b = *(const float4*)(p + 4);
  f16x8 r;
  r[0] = (_Float16)a.x; r[1] = (_Float16)a.y; r[2] = (_Float16)a.z; r[3] = (_Float16)a.w;
  r[4] = (_Float16)b.x; r[5] = (_Float16)b.y; r[6] = (_Float16)b.z; r[7] = (_Float16)b.w;
  return r;
}

// -------------------------------------------------- Wih2 transpose (once)
// WT[k*512 + h*4 + ti] = Wih2[(ti*128 + h)*128 + k]; 64K floats = 256 KB.
__global__ void w2t_kernel(const float* __restrict__ Wih2,
                           float* __restrict__ WT)
{
  int idx = blockIdx.x * 256 + threadIdx.x;      // 65536 total
  int k  = idx >> 9;
  int h  = (idx >> 2) & 127;
  int ti = idx & 3;
  WT[idx] = Wih2[(size_t)(ti * 128 + h) * 128 + k];
}

// ------------------------------------------------------------- fused SLSTM
__global__ __launch_bounds__(1024)
__attribute__((amdgpu_waves_per_eu(4, 4)))
void slstm_kernel(
    const float* __restrict__ x,      // [T,B,14]
    const float* __restrict__ Wih1,   // [512,14]
    const float* __restrict__ Whh1,   // [512,128]
    const float* __restrict__ bih1, const float* __restrict__ bhh1,
    const float* __restrict__ thr1p,
    const float* __restrict__ WT,     // [128,128,4] transposed Wih2
    const float* __restrict__ Whh2,   // [512,128]
    const float* __restrict__ bih2, const float* __restrict__ bhh2,
    const float* __restrict__ thr2p,
    float* __restrict__ sums)         // [B,H]
{
  const int b    = blockIdx.x;
  const int j    = threadIdx.x;
  const int lane = j & 63;
  const int w    = j >> 6;           // 0..15
  const int c    = lane & 15;        // MFMA col within tile / A-row (chunk)
  const int q    = lane >> 4;        // quad (k-slice / acc m-row group)
  const int qr   = (q ^ (c >> 2)) * 8;     // swizzled k-slot for mb reads

  __shared__ __align__(16) unsigned xb[T_STEPS * 8];         // 32 KB f16 pairs
  __shared__ __align__(16) unsigned short mb1[2][16 * 144];  // mem1 f16, dbuf
  __shared__ __align__(16) unsigned short mb2[2][16 * 144];  // mem2 f16, dbuf
  __shared__ __align__(16) unsigned short smk[2][16][8];     // spk1 bit-fields

  // ---- stage x as f16 pairs (14 data + 2 zero pads -> 8 words/row),
  //      word index swizzled by ((t>>6)&3)<<1 to spread MFMA-read banks
  for (int m = j; m < T_STEPS * 8; m += 1024) {
    int t = m >> 3, p = m & 7;
    unsigned v = 0;
    if (p < 7) {
      const float* xp = x + ((size_t)t * BATCH + b) * 14 + 2 * p;
      v = fpk(xp[0], xp[1]);
    }
    xb[(t << 3) | (p ^ (((t >> 6) & 3) << 1))] = v;
  }
  {
    unsigned* z1 = (unsigned*)mb1;
    unsigned* z2 = (unsigned*)mb2;
    for (int m = j; m < 2304; m += 1024) { z1[m] = 0; z2[m] = 0; }
    if (j < 128) ((unsigned*)smk)[j] = 0;
  }
  __syncthreads();

  if (w < 8) {
    // ================= layer-1 waves =================
    const int h   = w * 16 + c;
    const int hsw = h ^ (q << 3);
    f16x8 B1h[4][4];
    f16x4 B1x[4];
    float bias1v[4];
#pragma unroll
    for (int ti = 0; ti < 4; ++ti) {
      const int n = ti * 128 + h;
#pragma unroll
      for (int kt = 0; kt < 4; ++kt)
        B1h[ti][kt] = ldb8(Whh1 + (size_t)n * 128 + kt * 32 + q * 8);
      f16x4 bx;
#pragma unroll
      for (int e = 0; e < 4; ++e) {
        int k = q * 4 + e;
        bx[e] = (k < 14) ? (_Float16)Wih1[n * 14 + k] : (_Float16)0.f;
      }
      B1x[ti] = bx;
      bias1v[ti] = bih1[n] + bhh1[n];
    }
    const float thr1 = thr1p[0];
    float syn1[4] = {0,0,0,0}, mem1[4] = {0,0,0,0};

    for (int r = 0; r < NSTEP; ++r) {
      const int cb = r & 1, pb = cb ^ 1;
      if (r < NSTEP - 1) {
        int t1c = 64 * c - W_UP + r;
        if (t1c < 0) t1c = 0;
        f16x4 ax = *(const f16x4*)
            &xb[(t1c << 3) | ((2 * q) ^ (((t1c >> 6) & 3) << 1))];
        f16x8 A[4];
#pragma unroll
        for (int kt = 0; kt < 4; ++kt)
          A[kt] = *(const f16x8*)&mb1[pb][c * 144 + kt * 32 + qr];
        f32x4 acc[4];
#pragma unroll
        for (int ti = 0; ti < 4; ++ti) {
          acc[ti][0] = bias1v[ti]; acc[ti][1] = bias1v[ti];
          acc[ti][2] = bias1v[ti]; acc[ti][3] = bias1v[ti];
        }
        acc[0] = MFMAX(ax, B1x[0], acc[0]);
        acc[1] = MFMAX(ax, B1x[1], acc[1]);
        acc[2] = MFMAX(ax, B1x[2], acc[2]);
        acc[3] = MFMAX(ax, B1x[3], acc[3]);
#pragma unroll
        for (int kt = 0; kt < 4; ++kt) {
          acc[0] = MFMA16(A[kt], B1h[0][kt], acc[0]);
          acc[1] = MFMA16(A[kt], B1h[1][kt], acc[1]);
          acc[2] = MFMA16(A[kt], B1h[2][kt], acc[2]);
          acc[3] = MFMA16(A[kt], B1h[3][kt], acc[3]);
        }
        bool sp[4];
#pragma unroll
        for (int i = 0; i < 4; ++i) {
          float iv = fsig(acc[0][i]);
          float fv = fsig(acc[1][i]);
          float gv = ftanh(acc[2][i]);
          float ov = fsig(acc[3][i]);
          syn1[i] = fv * syn1[i] + iv * gv;
          float rst = (mem1[i] - thr1 > 0.f) ? thr1 : 0.f;  // detached pre-upd
          mem1[i] = ov * ftanh(syn1[i]) - rst;
          int t1 = 64 * (4 * q + i) - W_UP + r;
          if (t1 < 0) { syn1[i] = 0.f; mem1[i] = 0.f; }     // no history < 0
          sp[i] = (mem1[i] - thr1) > 0.f;
          mb1[cb][(4 * q + i) * 144 + hsw] = f16b(mem1[i]);
        }
        unsigned long long g0 = __ballot(sp[0]), g1 = __ballot(sp[1]);
        unsigned long long g2 = __ballot(sp[2]), g3 = __ballot(sp[3]);
        if (c == 0) {   // lane 16q extracts its q's 16-bit field
          smk[cb][4 * q + 0][w] = (unsigned short)(g0 >> (16 * q));
          smk[cb][4 * q + 1][w] = (unsigned short)(g1 >> (16 * q));
          smk[cb][4 * q + 2][w] = (unsigned short)(g2 >> (16 * q));
          smk[cb][4 * q + 3][w] = (unsigned short)(g3 >> (16 * q));
        }
      }
      __syncthreads();
    }
  } else {
    // ================= layer-2 waves =================
    const int h   = (w - 8) * 16 + c;
    const int hsw = h ^ (q << 3);
    f16x8 B2h[4][4];
    float bias2v[4];
#pragma unroll
    for (int ti = 0; ti < 4; ++ti) {
      const int n = ti * 128 + h;
#pragma unroll
      for (int kt = 0; kt < 4; ++kt)
        B2h[ti][kt] = ldb8(Whh2 + (size_t)n * 128 + kt * 32 + q * 8);
      bias2v[ti] = bih2[n] + bhh2[n];
    }
    const float thr2 = thr2p[0];
    const float* wt4 = WT + h * 4;   // + k*512
    float syn2[4] = {0,0,0,0}, mem2[4] = {0,0,0,0}, sum2[4] = {0,0,0,0};

    for (int r = 0; r < NSTEP; ++r) {
      const int cb = r & 1, pb = cb ^ 1;
      if (r > 0) {
        f32x4 acc[4];
#pragma unroll
        for (int ti = 0; ti < 4; ++ti) {
          acc[ti][0] = bias2v[ti]; acc[ti][1] = bias2v[ti];
          acc[ti][2] = bias2v[ti]; acc[ti][3] = bias2v[ti];
        }
        // spike input: one coalesced float4 (i,f,g,o weights) per set bit
#pragma unroll
        for (int i = 0; i < 4; ++i) {
          const unsigned long long* mp =
              (const unsigned long long*)&smk[pb][4 * q + i][0];
          unsigned long long m0 = mp[0], m1 = mp[1];
          float a0 = 0.f, a1 = 0.f, a2 = 0.f, a3 = 0.f;
          while (m0) {
            int k = __builtin_ctzll(m0); m0 &= m0 - 1;
            float4 v = *(const float4*)(wt4 + (k << 9));
            a0 += v.x; a1 += v.y; a2 += v.z; a3 += v.w;
          }
          while (m1) {
            int k = 64 + __builtin_ctzll(m1); m1 &= m1 - 1;
            float4 v = *(const float4*)(wt4 + (k << 9));
            a0 += v.x; a1 += v.y; a2 += v.z; a3 += v.w;
          }
          acc[0][i] += a0; acc[1][i] += a1; acc[2][i] += a2; acc[3][i] += a3;
        }
        f16x8 A[4];
#pragma unroll
        for (int kt = 0; kt < 4; ++kt)
          A[kt] = *(const f16x8*)&mb2[pb][c * 144 + kt * 32 + qr];
#pragma unroll
        for (int kt = 0; kt < 4; ++kt) {
          acc[0] = MFMA16(A[kt], B2h[0][kt], acc[0]);
          acc[1] = MFMA16(A[kt], B2h[1][kt], acc[1]);
          acc[2] = MFMA16(A[kt], B2h[2][kt], acc[2]);
          acc[3] = MFMA16(A[kt], B2h[3][kt], acc[3]);
        }
        const bool inwin = (r > W_UP);
#pragma unroll
        for (int i = 0; i < 4; ++i) {
          float iv = fsig(acc[0][i]);
          float fv = fsig(acc[1][i]);
          float gv = ftanh(acc[2][i]);
          float ov = fsig(acc[3][i]);
          syn2[i] = fv * syn2[i] + iv * gv;
          float rst = (mem2[i] - thr2 > 0.f) ? thr2 : 0.f;
          mem2[i] = ov * ftanh(syn2[i]) - rst;
          int t2 = 64 * (4 * q + i) - W_UP + r - 1;
          if (t2 < 0) { syn2[i] = 0.f; mem2[i] = 0.f; }
          if (inwin) sum2[i] += mem2[i];
          mb2[cb][(4 * q + i) * 144 + hsw] = f16b(mem2[i]);
        }
      }
      __syncthreads();
    }

    // ---- per-h reduction over the 4 q-groups: pure shuffle, no LDS
    float s = (sum2[0] + sum2[1]) + (sum2[2] + sum2[3]);
    s += __shfl_xor(s, 16);
    s += __shfl_xor(s, 32);
    if (q == 0)
      sums[(size_t)b * H + h] = s;
  }
}

// ---------------------------------------------------------------- readout
__global__ void fc_kernel(const float* __restrict__ sumbuf,  // [B,H]
                          const float* __restrict__ fcw,     // [NC,H]
                          const float* __restrict__ fcb,
                          float* __restrict__ out)           // [B,NC]
{
  int g = blockIdx.x * blockDim.x + threadIdx.x;
  if (g >= BATCH * NC) return;
  int b = g / NC, c = g % NC;
  const float* s = sumbuf + (size_t)b * H;
  const float* wr = fcw + c * H;
  float acc = 0.f;
#pragma unroll
  for (int hh = 0; hh < H; hh += 4) {
    float4 sv = *(const float4*)(s + hh);
    float4 wv = *(const float4*)(wr + hh);
    acc += sv.x * wv.x + sv.y * wv.y + sv.z * wv.z + sv.w * wv.w;
  }
  out[g] = fcb[c] + acc * (1.f / 1024.f);
}

extern "C" void kernel_launch(void* const* d_in, const int* in_sizes, int n_in,
                              void* d_out, int out_size, void* d_ws, size_t ws_size,
                              hipStream_t stream)
{
  (void)in_sizes; (void)n_in; (void)out_size; (void)ws_size;
  const float* x    = (const float*)d_in[0];
  const float* Wih1 = (const float*)d_in[1];
  const float* Whh1 = (const float*)d_in[2];
  const float* bih1 = (const float*)d_in[3];
  const float* bhh1 = (const float*)d_in[4];
  const float* thr1 = (const float*)d_in[5];
  const float* Wih2 = (const float*)d_in[6];
  const float* Whh2 = (const float*)d_in[7];
  const float* bih2 = (const float*)d_in[8];
  const float* bhh2 = (const float*)d_in[9];
  const float* thr2 = (const float*)d_in[10];
  const float* fcw  = (const float*)d_in[11];
  const float* fcb  = (const float*)d_in[12];

  float* sums = (float*)d_ws;                          // 128 KB
  float* WT   = (float*)((char*)d_ws + 128 * 1024);    // 256 KB

  w2t_kernel<<<256, 256, 0, stream>>>(Wih2, WT);
  slstm_kernel<<<256, 1024, 0, stream>>>(x, Wih1, Whh1, bih1, bhh1, thr1,
                                         WT, Whh2, bih2, bhh2, thr2, sums);
  fc_kernel<<<(BATCH * NC + 255) / 256, 256, 0, stream>>>(sums, fcw, fcb,
                                                          (float*)d_out);
}

// Round 6
// 277.868 us; speedup vs baseline: 5.3091x; 1.1448x over previous
//
#include <hip/hip_runtime.h>
#include <math.h>

// SLSTM: T=1024, B=256, C=14, H=128, 4H=512, NC=7. fp32 in/out.
//
// Round 17 = R16 (wave-specialized 16-wave block, 257 us steady) with:
//   - exp2 weight pre-scaling: all gate weights/biases carry log2(e)
//     (g-gate rows carry 2*log2e); activations are then pure
//     rcp(1+exp2(-a)) / 1-2*rcp(exp2(a)+1) -- the v_mul inside every
//     __expf disappears (HW exp IS exp2). syn-tanh keeps its one mul.
//   - W_UP 40 -> 32 (0.5^32 ~ 2e-10 initial-state leakage << f16 state
//     noise; absmax has been 0.0 since R12): NSTEP 105 -> 97.
//   - warm-up zeroing narrowed to its exact condition (chunk 0 only,
//     compile-time i==0): saves cmp+cndmask pairs on 7/8 chunks.
// Structure (waves 0-7 layer 1, waves 8-15 layer 2, smk/mb LDS flow,
// one barrier/step) unchanged from R16.

#define T_STEPS 1024
#define BATCH   256
#define H       128
#define NC      7
#define W_UP    32
#define NSTEP   (W_UP + 65)   // 97
#define L2E     1.44269504088896340736f

typedef __attribute__((ext_vector_type(8))) _Float16 f16x8;
typedef __attribute__((ext_vector_type(4))) _Float16 f16x4;
typedef __attribute__((ext_vector_type(4))) float f32x4;

__device__ __forceinline__ float frcp(float v) { return __builtin_amdgcn_rcpf(v); }
__device__ __forceinline__ float fex2(float v) { return __builtin_amdgcn_exp2f(v); }
// sigmoid(v) given a = L2E*v
__device__ __forceinline__ float fsig2(float a) { return frcp(1.f + fex2(-a)); }
// tanh(v) given a = 2*L2E*v
__device__ __forceinline__ float ftanh2(float a) {
  return 1.f - 2.f * frcp(fex2(a) + 1.f);
}
// tanh(v) from unscaled v (syn states)
__device__ __forceinline__ float ftanhs(float v) {
  return ftanh2(2.f * L2E * v);
}
__device__ __forceinline__ unsigned fpk(float a, float b) {
  unsigned lo = (unsigned)__builtin_bit_cast(unsigned short, (_Float16)a);
  unsigned hi = (unsigned)__builtin_bit_cast(unsigned short, (_Float16)b);
  return lo | (hi << 16);
}
__device__ __forceinline__ unsigned short f16b(float v) {
  return __builtin_bit_cast(unsigned short, (_Float16)v);
}
#define MFMA16(A, B, C) __builtin_amdgcn_mfma_f32_16x16x32_f16(A, B, C, 0, 0, 0)
#define MFMAX(A, B, C)  __builtin_amdgcn_mfma_f32_16x16x16f16(A, B, C, 0, 0, 0)

__device__ __forceinline__ f16x8 ldb8s(const float* p, float s) {
  float4 a = *(const float4*)p, b = *(const float4*)(p + 4);
  f16x8 r;
  r[0] = (_Float16)(a.x * s); r[1] = (_Float16)(a.y * s);
  r[2] = (_Float16)(a.z * s); r[3] = (_Float16)(a.w * s);
  r[4] = (_Float16)(b.x * s); r[5] = (_Float16)(b.y * s);
  r[6] = (_Float16)(b.z * s); r[7] = (_Float16)(b.w * s);
  return r;
}

// -------------------------------------------------- Wih2 transpose (once)
// WT[k*512 + h*4 + ti] = Wih2[(ti*128 + h)*128 + k] * scale(ti); 256 KB.
__global__ void w2t_kernel(const float* __restrict__ Wih2,
                           float* __restrict__ WT)
{
  int idx = blockIdx.x * 256 + threadIdx.x;      // 65536 total
  int k  = idx >> 9;
  int h  = (idx >> 2) & 127;
  int ti = idx & 3;
  float s = (ti == 2) ? 2.f * L2E : L2E;
  WT[idx] = Wih2[(size_t)(ti * 128 + h) * 128 + k] * s;
}

// ------------------------------------------------------------- fused SLSTM
__global__ __launch_bounds__(1024)
__attribute__((amdgpu_waves_per_eu(4, 4)))
void slstm_kernel(
    const float* __restrict__ x,      // [T,B,14]
    const float* __restrict__ Wih1,   // [512,14]
    const float* __restrict__ Whh1,   // [512,128]
    const float* __restrict__ bih1, const float* __restrict__ bhh1,
    const float* __restrict__ thr1p,
    const float* __restrict__ WT,     // [128,128,4] transposed+scaled Wih2
    const float* __restrict__ Whh2,   // [512,128]
    const float* __restrict__ bih2, const float* __restrict__ bhh2,
    const float* __restrict__ thr2p,
    float* __restrict__ sums)         // [B,H]
{
  const int b    = blockIdx.x;
  const int j    = threadIdx.x;
  const int lane = j & 63;
  const int w    = j >> 6;           // 0..15
  const int c    = lane & 15;        // MFMA col within tile / A-row (chunk)
  const int q    = lane >> 4;        // quad (k-slice / acc m-row group)
  const int qr   = (q ^ (c >> 2)) * 8;     // swizzled k-slot for mb reads

  __shared__ __align__(16) unsigned xb[T_STEPS * 8];         // 32 KB f16 pairs
  __shared__ __align__(16) unsigned short mb1[2][16 * 144];  // mem1 f16, dbuf
  __shared__ __align__(16) unsigned short mb2[2][16 * 144];  // mem2 f16, dbuf
  __shared__ __align__(16) unsigned short smk[2][16][8];     // spk1 bit-fields

  // ---- stage x as f16 pairs (14 data + 2 zero pads -> 8 words/row),
  //      word index swizzled by ((t>>6)&3)<<1 to spread MFMA-read banks
  for (int m = j; m < T_STEPS * 8; m += 1024) {
    int t = m >> 3, p = m & 7;
    unsigned v = 0;
    if (p < 7) {
      const float* xp = x + ((size_t)t * BATCH + b) * 14 + 2 * p;
      v = fpk(xp[0], xp[1]);
    }
    xb[(t << 3) | (p ^ (((t >> 6) & 3) << 1))] = v;
  }
  {
    unsigned* z1 = (unsigned*)mb1;
    unsigned* z2 = (unsigned*)mb2;
    for (int m = j; m < 2304; m += 1024) { z1[m] = 0; z2[m] = 0; }
    if (j < 128) ((unsigned*)smk)[j] = 0;
  }
  __syncthreads();

  if (w < 8) {
    // ================= layer-1 waves =================
    const int h   = w * 16 + c;
    const int hsw = h ^ (q << 3);
    f16x8 B1h[4][4];
    f16x4 B1x[4];
    float bias1v[4];
#pragma unroll
    for (int ti = 0; ti < 4; ++ti) {
      const float sc = (ti == 2) ? 2.f * L2E : L2E;
      const int n = ti * 128 + h;
#pragma unroll
      for (int kt = 0; kt < 4; ++kt)
        B1h[ti][kt] = ldb8s(Whh1 + (size_t)n * 128 + kt * 32 + q * 8, sc);
      f16x4 bx;
#pragma unroll
      for (int e = 0; e < 4; ++e) {
        int k = q * 4 + e;
        bx[e] = (k < 14) ? (_Float16)(Wih1[n * 14 + k] * sc) : (_Float16)0.f;
      }
      B1x[ti] = bx;
      bias1v[ti] = (bih1[n] + bhh1[n]) * sc;
    }
    const float thr1 = thr1p[0];
    const unsigned short* mr0 = &mb1[0][c * 144];
    const unsigned short* mr1 = &mb1[1][c * 144];
    float syn1[4] = {0,0,0,0}, mem1[4] = {0,0,0,0};

    for (int r = 0; r < NSTEP; ++r) {
      const int cb = r & 1, pb = cb ^ 1;
      if (r < NSTEP - 1) {
        int t1c = 64 * c - W_UP + r;
        if (t1c < 0) t1c = 0;
        f16x4 ax = *(const f16x4*)
            &xb[(t1c << 3) | ((2 * q) ^ (((t1c >> 6) & 3) << 1))];
        const unsigned short* src = pb ? mr1 : mr0;
        f16x8 A[4];
#pragma unroll
        for (int kt = 0; kt < 4; ++kt)
          A[kt] = *(const f16x8*)&src[kt * 32 + qr];
        f32x4 acc[4];
#pragma unroll
        for (int ti = 0; ti < 4; ++ti) {
          acc[ti][0] = bias1v[ti]; acc[ti][1] = bias1v[ti];
          acc[ti][2] = bias1v[ti]; acc[ti][3] = bias1v[ti];
        }
        acc[0] = MFMAX(ax, B1x[0], acc[0]);
        acc[1] = MFMAX(ax, B1x[1], acc[1]);
        acc[2] = MFMAX(ax, B1x[2], acc[2]);
        acc[3] = MFMAX(ax, B1x[3], acc[3]);
#pragma unroll
        for (int kt = 0; kt < 4; ++kt) {
          acc[0] = MFMA16(A[kt], B1h[0][kt], acc[0]);
          acc[1] = MFMA16(A[kt], B1h[1][kt], acc[1]);
          acc[2] = MFMA16(A[kt], B1h[2][kt], acc[2]);
          acc[3] = MFMA16(A[kt], B1h[3][kt], acc[3]);
        }
        bool sp[4];
#pragma unroll
        for (int i = 0; i < 4; ++i) {
          float iv = fsig2(acc[0][i]);
          float fv = fsig2(acc[1][i]);
          float gv = ftanh2(acc[2][i]);
          float ov = fsig2(acc[3][i]);
          syn1[i] = fv * syn1[i] + iv * gv;
          float rst = (mem1[i] - thr1 > 0.f) ? thr1 : 0.f;  // detached pre-upd
          mem1[i] = ov * ftanhs(syn1[i]) - rst;
          if (i == 0 && q == 0 && r < W_UP)                 // only chunk 0
            { syn1[0] = 0.f; mem1[0] = 0.f; }               // has t<0 here
          sp[i] = (mem1[i] - thr1) > 0.f;
          mb1[cb][(4 * q + i) * 144 + hsw] = f16b(mem1[i]);
        }
        unsigned long long g0 = __ballot(sp[0]), g1 = __ballot(sp[1]);
        unsigned long long g2 = __ballot(sp[2]), g3 = __ballot(sp[3]);
        if (c == 0) {   // lane 16q extracts its q's 16-bit field
          smk[cb][4 * q + 0][w] = (unsigned short)(g0 >> (16 * q));
          smk[cb][4 * q + 1][w] = (unsigned short)(g1 >> (16 * q));
          smk[cb][4 * q + 2][w] = (unsigned short)(g2 >> (16 * q));
          smk[cb][4 * q + 3][w] = (unsigned short)(g3 >> (16 * q));
        }
      }
      __syncthreads();
    }
  } else {
    // ================= layer-2 waves =================
    const int h   = (w - 8) * 16 + c;
    const int hsw = h ^ (q << 3);
    f16x8 B2h[4][4];
    float bias2v[4];
#pragma unroll
    for (int ti = 0; ti < 4; ++ti) {
      const float sc = (ti == 2) ? 2.f * L2E : L2E;
      const int n = ti * 128 + h;
#pragma unroll
      for (int kt = 0; kt < 4; ++kt)
        B2h[ti][kt] = ldb8s(Whh2 + (size_t)n * 128 + kt * 32 + q * 8, sc);
      bias2v[ti] = (bih2[n] + bhh2[n]) * sc;
    }
    const float thr2 = thr2p[0];
    const float* wt4 = WT + h * 4;   // + k*512
    const unsigned short* mr0 = &mb2[0][c * 144];
    const unsigned short* mr1 = &mb2[1][c * 144];
    float syn2[4] = {0,0,0,0}, mem2[4] = {0,0,0,0}, sum2[4] = {0,0,0,0};

    for (int r = 0; r < NSTEP; ++r) {
      const int cb = r & 1, pb = cb ^ 1;
      if (r > 0) {
        f32x4 acc[4];
#pragma unroll
        for (int ti = 0; ti < 4; ++ti) {
          acc[ti][0] = bias2v[ti]; acc[ti][1] = bias2v[ti];
          acc[ti][2] = bias2v[ti]; acc[ti][3] = bias2v[ti];
        }
        // spike input: one coalesced float4 (i,f,g,o weights) per set bit
#pragma unroll
        for (int i = 0; i < 4; ++i) {
          const unsigned long long* mp =
              (const unsigned long long*)&smk[pb][4 * q + i][0];
          unsigned long long m0 = mp[0], m1 = mp[1];
          float a0 = 0.f, a1 = 0.f, a2 = 0.f, a3 = 0.f;
          while (m0) {
            int k = __builtin_ctzll(m0); m0 &= m0 - 1;
            float4 v = *(const float4*)(wt4 + (k << 9));
            a0 += v.x; a1 += v.y; a2 += v.z; a3 += v.w;
          }
          while (m1) {
            int k = 64 + __builtin_ctzll(m1); m1 &= m1 - 1;
            float4 v = *(const float4*)(wt4 + (k << 9));
            a0 += v.x; a1 += v.y; a2 += v.z; a3 += v.w;
          }
          acc[0][i] += a0; acc[1][i] += a1; acc[2][i] += a2; acc[3][i] += a3;
        }
        f16x8 A[4];
        const unsigned short* src = pb ? mr1 : mr0;
#pragma unroll
        for (int kt = 0; kt < 4; ++kt)
          A[kt] = *(const f16x8*)&src[kt * 32 + qr];
#pragma unroll
        for (int kt = 0; kt < 4; ++kt) {
          acc[0] = MFMA16(A[kt], B2h[0][kt], acc[0]);
          acc[1] = MFMA16(A[kt], B2h[1][kt], acc[1]);
          acc[2] = MFMA16(A[kt], B2h[2][kt], acc[2]);
          acc[3] = MFMA16(A[kt], B2h[3][kt], acc[3]);
        }
        const bool inwin = (r > W_UP);
#pragma unroll
        for (int i = 0; i < 4; ++i) {
          float iv = fsig2(acc[0][i]);
          float fv = fsig2(acc[1][i]);
          float gv = ftanh2(acc[2][i]);
          float ov = fsig2(acc[3][i]);
          syn2[i] = fv * syn2[i] + iv * gv;
          float rst = (mem2[i] - thr2 > 0.f) ? thr2 : 0.f;
          mem2[i] = ov * ftanhs(syn2[i]) - rst;
          if (i == 0 && q == 0 && r <= W_UP)                // only chunk 0
            { syn2[0] = 0.f; mem2[0] = 0.f; }               // has t<0 here
          if (inwin) sum2[i] += mem2[i];
          mb2[cb][(4 * q + i) * 144 + hsw] = f16b(mem2[i]);
        }
      }
      __syncthreads();
    }

    // ---- per-h reduction over the 4 q-groups: pure shuffle, no LDS
    float s = (sum2[0] + sum2[1]) + (sum2[2] + sum2[3]);
    s += __shfl_xor(s, 16);
    s += __shfl_xor(s, 32);
    if (q == 0)
      sums[(size_t)b * H + h] = s;
  }
}

// ---------------------------------------------------------------- readout
__global__ void fc_kernel(const float* __restrict__ sumbuf,  // [B,H]
                          const float* __restrict__ fcw,     // [NC,H]
                          const float* __restrict__ fcb,
                          float* __restrict__ out)           // [B,NC]
{
  int g = blockIdx.x * blockDim.x + threadIdx.x;
  if (g >= BATCH * NC) return;
  int b = g / NC, c = g % NC;
  const float* s = sumbuf + (size_t)b * H;
  const float* wr = fcw + c * H;
  float acc = 0.f;
#pragma unroll
  for (int hh = 0; hh < H; hh += 4) {
    float4 sv = *(const float4*)(s + hh);
    float4 wv = *(const float4*)(wr + hh);
    acc += sv.x * wv.x + sv.y * wv.y + sv.z * wv.z + sv.w * wv.w;
  }
  out[g] = fcb[c] + acc * (1.f / 1024.f);
}

extern "C" void kernel_launch(void* const* d_in, const int* in_sizes, int n_in,
                              void* d_out, int out_size, void* d_ws, size_t ws_size,
                              hipStream_t stream)
{
  (void)in_sizes; (void)n_in; (void)out_size; (void)ws_size;
  const float* x    = (const float*)d_in[0];
  const float* Wih1 = (const float*)d_in[1];
  const float* Whh1 = (const float*)d_in[2];
  const float* bih1 = (const float*)d_in[3];
  const float* bhh1 = (const float*)d_in[4];
  const float* thr1 = (const float*)d_in[5];
  const float* Wih2 = (const float*)d_in[6];
  const float* Whh2 = (const float*)d_in[7];
  const float* bih2 = (const float*)d_in[8];
  const float* bhh2 = (const float*)d_in[9];
  const float* thr2 = (const float*)d_in[10];
  const float* fcw  = (const float*)d_in[11];
  const float* fcb  = (const float*)d_in[12];

  float* sums = (float*)d_ws;                          // 128 KB
  float* WT   = (float*)((char*)d_ws + 128 * 1024);    // 256 KB

  w2t_kernel<<<256, 256, 0, stream>>>(Wih2, WT);
  slstm_kernel<<<256, 1024, 0, stream>>>(x, Wih1, Whh1, bih1, bhh1, thr1,
                                         WT, Whh2, bih2, bhh2, thr2, sums);
  fc_kernel<<<(BATCH * NC + 255) / 256, 256, 0, stream>>>(sums, fcw, fcb,
                                                          (float*)d_out);
}

// Round 7
// 134.585 us; speedup vs baseline: 10.9614x; 2.0646x over previous
//
#include <hip/hip_runtime.h>
#include <math.h>

// SLSTM: T=1024, B=256, C=14, H=128, 4H=512, NC=7. fp32 in/out.
//
// Round 18 = R17 + runtime-guarded degenerate fast path.
//
// KEY FACT (exact, not approximate): mem = sigmoid(o)*tanh(syn) - reset with
// sigmoid<=1, tanh<=1 (both saturate at exactly 1.0 in f32; product rounds
// to <=1.0) and reset>=0, so mem <= 1.0 ALWAYS. The spike test is STRICT
// (mem - thr > 0), so for thr1 >= 1.0 layer-1 spikes can never fire -- in
// the reference too. Then layer 2's input is identically zero: its dynamics
// are autonomous and batch-independent, the output is one 7-vector broadcast
// across the batch, and layer 1 + x are dead code.
//
// All kernels read thr1 at runtime and branch uniformly:
//   thr1 >= 1.0 : w2t + full slstm exit; slstm_degen (4 blocks, 64 chunks x
//                 16 steps, W_UP=32, NSTEP=48; R17's L2 MFMA step verbatim
//                 minus spikes/batch) computes the single mem2 trajectory;
//                 fc broadcasts one dot product.
//   thr1 <  1.0 : exact R17 path (full kernel + WT spike loop) -- honest
//                 fallback for any spiking regime.

#define T_STEPS 1024
#define BATCH   256
#define H       128
#define NC      7
#define W_UP    32
#define NSTEP   (W_UP + 65)   // 97  (full kernel)
#define DCHUNK  16
#define DNSTEP  (W_UP + DCHUNK)   // 48 (degen kernel)
#define L2E     1.44269504088896340736f

typedef __attribute__((ext_vector_type(8))) _Float16 f16x8;
typedef __attribute__((ext_vector_type(4))) _Float16 f16x4;
typedef __attribute__((ext_vector_type(4))) float f32x4;

__device__ __forceinline__ float frcp(float v) { return __builtin_amdgcn_rcpf(v); }
__device__ __forceinline__ float fex2(float v) { return __builtin_amdgcn_exp2f(v); }
// sigmoid(v) given a = L2E*v
__device__ __forceinline__ float fsig2(float a) { return frcp(1.f + fex2(-a)); }
// tanh(v) given a = 2*L2E*v
__device__ __forceinline__ float ftanh2(float a) {
  return 1.f - 2.f * frcp(fex2(a) + 1.f);
}
// tanh(v) from unscaled v (syn states)
__device__ __forceinline__ float ftanhs(float v) {
  return ftanh2(2.f * L2E * v);
}
__device__ __forceinline__ unsigned fpk(float a, float b) {
  unsigned lo = (unsigned)__builtin_bit_cast(unsigned short, (_Float16)a);
  unsigned hi = (unsigned)__builtin_bit_cast(unsigned short, (_Float16)b);
  return lo | (hi << 16);
}
__device__ __forceinline__ unsigned short f16b(float v) {
  return __builtin_bit_cast(unsigned short, (_Float16)v);
}
#define MFMA16(A, B, C) __builtin_amdgcn_mfma_f32_16x16x32_f16(A, B, C, 0, 0, 0)
#define MFMAX(A, B, C)  __builtin_amdgcn_mfma_f32_16x16x16f16(A, B, C, 0, 0, 0)

__device__ __forceinline__ f16x8 ldb8s(const float* p, float s) {
  float4 a = *(const float4*)p, b = *(const float4*)(p + 4);
  f16x8 r;
  r[0] = (_Float16)(a.x * s); r[1] = (_Float16)(a.y * s);
  r[2] = (_Float16)(a.z * s); r[3] = (_Float16)(a.w * s);
  r[4] = (_Float16)(b.x * s); r[5] = (_Float16)(b.y * s);
  r[6] = (_Float16)(b.z * s); r[7] = (_Float16)(b.w * s);
  return r;
}

// -------------------------------------------------- Wih2 transpose (once)
__global__ void w2t_kernel(const float* __restrict__ Wih2,
                           float* __restrict__ WT,
                           const float* __restrict__ thr1p)
{
  if (thr1p[0] >= 1.0f) return;    // fast path: WT never used
  int idx = blockIdx.x * 256 + threadIdx.x;      // 65536 total
  int k  = idx >> 9;
  int h  = (idx >> 2) & 127;
  int ti = idx & 3;
  float s = (ti == 2) ? 2.f * L2E : L2E;
  WT[idx] = Wih2[(size_t)(ti * 128 + h) * 128 + k] * s;
}

// ---------------------------------------------- degenerate layer-2 kernel
// 64 independent chunks of 16 t-steps, 4 blocks x 16 chunks. Per-step code
// is R17's layer-2 path verbatim minus spike input and batch index.
__global__ __launch_bounds__(512)
void slstm_degen(const float* __restrict__ Whh2,
                 const float* __restrict__ bih2, const float* __restrict__ bhh2,
                 const float* __restrict__ thr1p, const float* __restrict__ thr2p,
                 float* __restrict__ sums2)       // [4,H]
{
  if (thr1p[0] < 1.0f) return;     // spiking regime: full kernel handles it
  const int p    = blockIdx.x;     // owns global chunks 16p..16p+15
  const int j    = threadIdx.x;
  const int lane = j & 63;
  const int w    = j >> 6;         // 0..7
  const int c    = lane & 15;
  const int q    = lane >> 4;
  const int qr   = (q ^ (c >> 2)) * 8;
  const int h    = w * 16 + c;
  const int hsw  = h ^ (q << 3);

  __shared__ __align__(16) unsigned short mb2[2][16 * 144];

  f16x8 B2h[4][4];
  float bias2v[4];
#pragma unroll
  for (int ti = 0; ti < 4; ++ti) {
    const float sc = (ti == 2) ? 2.f * L2E : L2E;
    const int n = ti * 128 + h;
#pragma unroll
    for (int kt = 0; kt < 4; ++kt)
      B2h[ti][kt] = ldb8s(Whh2 + (size_t)n * 128 + kt * 32 + q * 8, sc);
    bias2v[ti] = (bih2[n] + bhh2[n]) * sc;
  }
  const float thr2 = thr2p[0];
  {
    unsigned* z = (unsigned*)mb2;
    for (int m = j; m < 2304; m += 512) z[m] = 0;
  }
  const unsigned short* mr0 = &mb2[0][c * 144];
  const unsigned short* mr1 = &mb2[1][c * 144];
  float syn2[4] = {0,0,0,0}, mem2[4] = {0,0,0,0}, sum2[4] = {0,0,0,0};
  __syncthreads();

  for (int r = 0; r < DNSTEP; ++r) {
    const int cb = r & 1, pb = cb ^ 1;
    f16x8 A[4];
    const unsigned short* src = pb ? mr1 : mr0;
#pragma unroll
    for (int kt = 0; kt < 4; ++kt)
      A[kt] = *(const f16x8*)&src[kt * 32 + qr];
    f32x4 acc[4];
#pragma unroll
    for (int ti = 0; ti < 4; ++ti) {
      acc[ti][0] = bias2v[ti]; acc[ti][1] = bias2v[ti];
      acc[ti][2] = bias2v[ti]; acc[ti][3] = bias2v[ti];
    }
#pragma unroll
    for (int kt = 0; kt < 4; ++kt) {
      acc[0] = MFMA16(A[kt], B2h[0][kt], acc[0]);
      acc[1] = MFMA16(A[kt], B2h[1][kt], acc[1]);
      acc[2] = MFMA16(A[kt], B2h[2][kt], acc[2]);
      acc[3] = MFMA16(A[kt], B2h[3][kt], acc[3]);
    }
    const bool inwin = (r >= W_UP);
#pragma unroll
    for (int i = 0; i < 4; ++i) {
      float iv = fsig2(acc[0][i]);
      float fv = fsig2(acc[1][i]);
      float gv = ftanh2(acc[2][i]);
      float ov = fsig2(acc[3][i]);
      syn2[i] = fv * syn2[i] + iv * gv;
      float rst = (mem2[i] - thr2 > 0.f) ? thr2 : 0.f;
      mem2[i] = ov * ftanhs(syn2[i]) - rst;
      if (i == 0 && q == 0 && p == 0 && r < W_UP)   // global chunk 0: t<0
        { syn2[0] = 0.f; mem2[0] = 0.f; }
      if (inwin) sum2[i] += mem2[i];
      mb2[cb][(4 * q + i) * 144 + hsw] = f16b(mem2[i]);
    }
    __syncthreads();
  }

  float s = (sum2[0] + sum2[1]) + (sum2[2] + sum2[3]);
  s += __shfl_xor(s, 16);
  s += __shfl_xor(s, 32);
  if (q == 0)
    sums2[(size_t)p * H + h] = s;
}

// ------------------------------------------------------------- fused SLSTM
__global__ __launch_bounds__(1024)
__attribute__((amdgpu_waves_per_eu(4, 4)))
void slstm_kernel(
    const float* __restrict__ x,      // [T,B,14]
    const float* __restrict__ Wih1,   // [512,14]
    const float* __restrict__ Whh1,   // [512,128]
    const float* __restrict__ bih1, const float* __restrict__ bhh1,
    const float* __restrict__ thr1p,
    const float* __restrict__ WT,     // [128,128,4] transposed+scaled Wih2
    const float* __restrict__ Whh2,   // [512,128]
    const float* __restrict__ bih2, const float* __restrict__ bhh2,
    const float* __restrict__ thr2p,
    float* __restrict__ sums)         // [B,H]
{
  const float thr1 = thr1p[0];
  if (thr1 >= 1.0f) return;          // degenerate path handles it
  const int b    = blockIdx.x;
  const int j    = threadIdx.x;
  const int lane = j & 63;
  const int w    = j >> 6;           // 0..15
  const int c    = lane & 15;        // MFMA col within tile / A-row (chunk)
  const int q    = lane >> 4;        // quad (k-slice / acc m-row group)
  const int qr   = (q ^ (c >> 2)) * 8;     // swizzled k-slot for mb reads

  __shared__ __align__(16) unsigned xb[T_STEPS * 8];         // 32 KB f16 pairs
  __shared__ __align__(16) unsigned short mb1[2][16 * 144];  // mem1 f16, dbuf
  __shared__ __align__(16) unsigned short mb2[2][16 * 144];  // mem2 f16, dbuf
  __shared__ __align__(16) unsigned short smk[2][16][8];     // spk1 bit-fields

  for (int m = j; m < T_STEPS * 8; m += 1024) {
    int t = m >> 3, p = m & 7;
    unsigned v = 0;
    if (p < 7) {
      const float* xp = x + ((size_t)t * BATCH + b) * 14 + 2 * p;
      v = fpk(xp[0], xp[1]);
    }
    xb[(t << 3) | (p ^ (((t >> 6) & 3) << 1))] = v;
  }
  {
    unsigned* z1 = (unsigned*)mb1;
    unsigned* z2 = (unsigned*)mb2;
    for (int m = j; m < 2304; m += 1024) { z1[m] = 0; z2[m] = 0; }
    if (j < 128) ((unsigned*)smk)[j] = 0;
  }
  __syncthreads();

  if (w < 8) {
    // ================= layer-1 waves =================
    const int h   = w * 16 + c;
    const int hsw = h ^ (q << 3);
    f16x8 B1h[4][4];
    f16x4 B1x[4];
    float bias1v[4];
#pragma unroll
    for (int ti = 0; ti < 4; ++ti) {
      const float sc = (ti == 2) ? 2.f * L2E : L2E;
      const int n = ti * 128 + h;
#pragma unroll
      for (int kt = 0; kt < 4; ++kt)
        B1h[ti][kt] = ldb8s(Whh1 + (size_t)n * 128 + kt * 32 + q * 8, sc);
      f16x4 bx;
#pragma unroll
      for (int e = 0; e < 4; ++e) {
        int k = q * 4 + e;
        bx[e] = (k < 14) ? (_Float16)(Wih1[n * 14 + k] * sc) : (_Float16)0.f;
      }
      B1x[ti] = bx;
      bias1v[ti] = (bih1[n] + bhh1[n]) * sc;
    }
    const unsigned short* mr0 = &mb1[0][c * 144];
    const unsigned short* mr1 = &mb1[1][c * 144];
    float syn1[4] = {0,0,0,0}, mem1[4] = {0,0,0,0};

    for (int r = 0; r < NSTEP; ++r) {
      const int cb = r & 1, pb = cb ^ 1;
      if (r < NSTEP - 1) {
        int t1c = 64 * c - W_UP + r;
        if (t1c < 0) t1c = 0;
        f16x4 ax = *(const f16x4*)
            &xb[(t1c << 3) | ((2 * q) ^ (((t1c >> 6) & 3) << 1))];
        const unsigned short* src = pb ? mr1 : mr0;
        f16x8 A[4];
#pragma unroll
        for (int kt = 0; kt < 4; ++kt)
          A[kt] = *(const f16x8*)&src[kt * 32 + qr];
        f32x4 acc[4];
#pragma unroll
        for (int ti = 0; ti < 4; ++ti) {
          acc[ti][0] = bias1v[ti]; acc[ti][1] = bias1v[ti];
          acc[ti][2] = bias1v[ti]; acc[ti][3] = bias1v[ti];
        }
        acc[0] = MFMAX(ax, B1x[0], acc[0]);
        acc[1] = MFMAX(ax, B1x[1], acc[1]);
        acc[2] = MFMAX(ax, B1x[2], acc[2]);
        acc[3] = MFMAX(ax, B1x[3], acc[3]);
#pragma unroll
        for (int kt = 0; kt < 4; ++kt) {
          acc[0] = MFMA16(A[kt], B1h[0][kt], acc[0]);
          acc[1] = MFMA16(A[kt], B1h[1][kt], acc[1]);
          acc[2] = MFMA16(A[kt], B1h[2][kt], acc[2]);
          acc[3] = MFMA16(A[kt], B1h[3][kt], acc[3]);
        }
        bool sp[4];
#pragma unroll
        for (int i = 0; i < 4; ++i) {
          float iv = fsig2(acc[0][i]);
          float fv = fsig2(acc[1][i]);
          float gv = ftanh2(acc[2][i]);
          float ov = fsig2(acc[3][i]);
          syn1[i] = fv * syn1[i] + iv * gv;
          float rst = (mem1[i] - thr1 > 0.f) ? thr1 : 0.f;  // detached pre-upd
          mem1[i] = ov * ftanhs(syn1[i]) - rst;
          if (i == 0 && q == 0 && r < W_UP)                 // only chunk 0
            { syn1[0] = 0.f; mem1[0] = 0.f; }               // has t<0 here
          sp[i] = (mem1[i] - thr1) > 0.f;
          mb1[cb][(4 * q + i) * 144 + hsw] = f16b(mem1[i]);
        }
        unsigned long long g0 = __ballot(sp[0]), g1 = __ballot(sp[1]);
        unsigned long long g2 = __ballot(sp[2]), g3 = __ballot(sp[3]);
        if (c == 0) {   // lane 16q extracts its q's 16-bit field
          smk[cb][4 * q + 0][w] = (unsigned short)(g0 >> (16 * q));
          smk[cb][4 * q + 1][w] = (unsigned short)(g1 >> (16 * q));
          smk[cb][4 * q + 2][w] = (unsigned short)(g2 >> (16 * q));
          smk[cb][4 * q + 3][w] = (unsigned short)(g3 >> (16 * q));
        }
      }
      __syncthreads();
    }
  } else {
    // ================= layer-2 waves =================
    const int h   = (w - 8) * 16 + c;
    const int hsw = h ^ (q << 3);
    f16x8 B2h[4][4];
    float bias2v[4];
#pragma unroll
    for (int ti = 0; ti < 4; ++ti) {
      const float sc = (ti == 2) ? 2.f * L2E : L2E;
      const int n = ti * 128 + h;
#pragma unroll
      for (int kt = 0; kt < 4; ++kt)
        B2h[ti][kt] = ldb8s(Whh2 + (size_t)n * 128 + kt * 32 + q * 8, sc);
      bias2v[ti] = (bih2[n] + bhh2[n]) * sc;
    }
    const float thr2 = thr2p[0];
    const float* wt4 = WT + h * 4;   // + k*512
    const unsigned short* mr0 = &mb2[0][c * 144];
    const unsigned short* mr1 = &mb2[1][c * 144];
    float syn2[4] = {0,0,0,0}, mem2[4] = {0,0,0,0}, sum2[4] = {0,0,0,0};

    for (int r = 0; r < NSTEP; ++r) {
      const int cb = r & 1, pb = cb ^ 1;
      if (r > 0) {
        f32x4 acc[4];
#pragma unroll
        for (int ti = 0; ti < 4; ++ti) {
          acc[ti][0] = bias2v[ti]; acc[ti][1] = bias2v[ti];
          acc[ti][2] = bias2v[ti]; acc[ti][3] = bias2v[ti];
        }
        // spike input: one coalesced float4 (i,f,g,o weights) per set bit
#pragma unroll
        for (int i = 0; i < 4; ++i) {
          const unsigned long long* mp =
              (const unsigned long long*)&smk[pb][4 * q + i][0];
          unsigned long long m0 = mp[0], m1 = mp[1];
          float a0 = 0.f, a1 = 0.f, a2 = 0.f, a3 = 0.f;
          while (m0) {
            int k = __builtin_ctzll(m0); m0 &= m0 - 1;
            float4 v = *(const float4*)(wt4 + (k << 9));
            a0 += v.x; a1 += v.y; a2 += v.z; a3 += v.w;
          }
          while (m1) {
            int k = 64 + __builtin_ctzll(m1); m1 &= m1 - 1;
            float4 v = *(const float4*)(wt4 + (k << 9));
            a0 += v.x; a1 += v.y; a2 += v.z; a3 += v.w;
          }
          acc[0][i] += a0; acc[1][i] += a1; acc[2][i] += a2; acc[3][i] += a3;
        }
        f16x8 A[4];
        const unsigned short* src = pb ? mr1 : mr0;
#pragma unroll
        for (int kt = 0; kt < 4; ++kt)
          A[kt] = *(const f16x8*)&src[kt * 32 + qr];
#pragma unroll
        for (int kt = 0; kt < 4; ++kt) {
          acc[0] = MFMA16(A[kt], B2h[0][kt], acc[0]);
          acc[1] = MFMA16(A[kt], B2h[1][kt], acc[1]);
          acc[2] = MFMA16(A[kt], B2h[2][kt], acc[2]);
          acc[3] = MFMA16(A[kt], B2h[3][kt], acc[3]);
        }
        const bool inwin = (r > W_UP);
#pragma unroll
        for (int i = 0; i < 4; ++i) {
          float iv = fsig2(acc[0][i]);
          float fv = fsig2(acc[1][i]);
          float gv = ftanh2(acc[2][i]);
          float ov = fsig2(acc[3][i]);
          syn2[i] = fv * syn2[i] + iv * gv;
          float rst = (mem2[i] - thr2 > 0.f) ? thr2 : 0.f;
          mem2[i] = ov * ftanhs(syn2[i]) - rst;
          if (i == 0 && q == 0 && r <= W_UP)                // only chunk 0
            { syn2[0] = 0.f; mem2[0] = 0.f; }               // has t<0 here
          if (inwin) sum2[i] += mem2[i];
          mb2[cb][(4 * q + i) * 144 + hsw] = f16b(mem2[i]);
        }
      }
      __syncthreads();
    }

    // ---- per-h reduction over the 4 q-groups: pure shuffle, no LDS
    float s = (sum2[0] + sum2[1]) + (sum2[2] + sum2[3]);
    s += __shfl_xor(s, 16);
    s += __shfl_xor(s, 32);
    if (q == 0)
      sums[(size_t)b * H + h] = s;
  }
}

// ---------------------------------------------------------------- readout
__global__ void fc_kernel(const float* __restrict__ sumbuf,  // [B,H] (fallback)
                          const float* __restrict__ sums2,   // [4,H] (fast)
                          const float* __restrict__ thr1p,
                          const float* __restrict__ fcw,     // [NC,H]
                          const float* __restrict__ fcb,
                          float* __restrict__ out)           // [B,NC]
{
  int g = blockIdx.x * blockDim.x + threadIdx.x;
  if (g >= BATCH * NC) return;
  int b = g / NC, c = g % NC;
  const float* wr = fcw + c * H;
  float acc = 0.f;
  if (thr1p[0] >= 1.0f) {
    // batch-independent: sum the 4 degen partials, one dot, broadcast
#pragma unroll
    for (int hh = 0; hh < H; hh += 4) {
      float4 s0 = *(const float4*)(sums2 + hh);
      float4 s1 = *(const float4*)(sums2 + H + hh);
      float4 s2 = *(const float4*)(sums2 + 2 * H + hh);
      float4 s3 = *(const float4*)(sums2 + 3 * H + hh);
      float4 wv = *(const float4*)(wr + hh);
      acc += (s0.x + s1.x + s2.x + s3.x) * wv.x
           + (s0.y + s1.y + s2.y + s3.y) * wv.y
           + (s0.z + s1.z + s2.z + s3.z) * wv.z
           + (s0.w + s1.w + s2.w + s3.w) * wv.w;
    }
  } else {
    const float* s = sumbuf + (size_t)b * H;
#pragma unroll
    for (int hh = 0; hh < H; hh += 4) {
      float4 sv = *(const float4*)(s + hh);
      float4 wv = *(const float4*)(wr + hh);
      acc += sv.x * wv.x + sv.y * wv.y + sv.z * wv.z + sv.w * wv.w;
    }
  }
  out[g] = fcb[c] + acc * (1.f / 1024.f);
}

extern "C" void kernel_launch(void* const* d_in, const int* in_sizes, int n_in,
                              void* d_out, int out_size, void* d_ws, size_t ws_size,
                              hipStream_t stream)
{
  (void)in_sizes; (void)n_in; (void)out_size; (void)ws_size;
  const float* x    = (const float*)d_in[0];
  const float* Wih1 = (const float*)d_in[1];
  const float* Whh1 = (const float*)d_in[2];
  const float* bih1 = (const float*)d_in[3];
  const float* bhh1 = (const float*)d_in[4];
  const float* thr1 = (const float*)d_in[5];
  const float* Wih2 = (const float*)d_in[6];
  const float* Whh2 = (const float*)d_in[7];
  const float* bih2 = (const float*)d_in[8];
  const float* bhh2 = (const float*)d_in[9];
  const float* thr2 = (const float*)d_in[10];
  const float* fcw  = (const float*)d_in[11];
  const float* fcb  = (const float*)d_in[12];

  float* sums  = (float*)d_ws;                           // 128 KB (fallback)
  float* WT    = (float*)((char*)d_ws + 128 * 1024);     // 256 KB (fallback)
  float* sums2 = (float*)((char*)d_ws + 384 * 1024);     // 2 KB  (fast)

  w2t_kernel<<<256, 256, 0, stream>>>(Wih2, WT, thr1);
  slstm_kernel<<<256, 1024, 0, stream>>>(x, Wih1, Whh1, bih1, bhh1, thr1,
                                         WT, Whh2, bih2, bhh2, thr2, sums);
  slstm_degen<<<4, 512, 0, stream>>>(Whh2, bih2, bhh2, thr1, thr2, sums2);
  fc_kernel<<<(BATCH * NC + 255) / 256, 256, 0, stream>>>(sums, sums2, thr1,
                                                          fcw, fcb,
                                                          (float*)d_out);
}